// Round 11
// baseline (611.749 us; speedup 1.0000x reference)
//
#include <hip/hip_runtime.h>
#include <hip/hip_bf16.h>
#include <math.h>

#define F_IN   128
#define HID    128
#define HEADS  4
#define HC1    (HEADS*HID)   // 512
#define CLASSES 2
#define NEG_SLOPE 0.2f
#define LOG2E 1.44269504088896340736f
#define MNEG  -3.0e38f

#define SCAN_CHUNK 2048
#define NB_SCAN 25           // ceil(50000/2048)

typedef __attribute__((ext_vector_type(8))) short short8;
typedef __attribute__((ext_vector_type(4))) float f32x4;
typedef __attribute__((ext_vector_type(2))) float f32x2;

__device__ __forceinline__ f32x2 unpack2(unsigned u) {
    f32x2 r;
    r.x = __uint_as_float(u << 16);
    r.y = __uint_as_float(u & 0xffff0000u);
    return r;
}

__device__ __forceinline__ uint4 nt_load_u4(const unsigned* p) {
    uint4 r;
    r.x = __builtin_nontemporal_load(p);
    r.y = __builtin_nontemporal_load(p + 1);
    r.z = __builtin_nontemporal_load(p + 2);
    r.w = __builtin_nontemporal_load(p + 3);
    return r;
}

// ---------------------------------------------------------------------------
// device bodies for fused block-specialized kernels
// ---------------------------------------------------------------------------
__device__ void zero_body(int vb, int nvb, int* __restrict__ p, int n) {
    int i = vb * 256 + threadIdx.x;
    int stride = nvb * 256;
    for (; i < n; i += stride) p[i] = 0;
}

__device__ void deg_body(int vb, const int* __restrict__ dst_arr,
                         int* __restrict__ deg, int E, int N) {
    int e = vb * 256 + threadIdx.x;
    if (e >= E) return;
    int d = dst_arr[e];
    if ((unsigned)d >= (unsigned)N) d = 0;
    atomicAdd(&deg[d], 1);
}

__device__ void weights_prep_body(int vb,
    const float* __restrict__ w_in, const float* __restrict__ wl1,
    const float* __restrict__ wr1, const float* __restrict__ wl2,
    const float* __restrict__ wr2,
    __hip_bfloat16* __restrict__ w_inT, __hip_bfloat16* __restrict__ wT1,
    __hip_bfloat16* __restrict__ wT2)
{
    int t = vb * 256 + threadIdx.x;
    const int S0 = 128 * 128, S1 = 128 * 512;
    if (t < S0) {
        int n = t / 128, k = t % 128;
        w_inT[t] = __float2bfloat16(w_in[(size_t)k * 128 + n]);
    } else if (t < S0 + S1) {
        int idx = t - S0;
        int n = idx / 128, k = idx % 128;
        wT1[idx] = __float2bfloat16(wl1[(size_t)k * 512 + n]);
    } else if (t < S0 + 2 * S1) {
        int idx = t - S0 - S1;
        int n = idx / 128, k = idx % 128;
        wT1[(size_t)(512 + n) * 128 + k] = __float2bfloat16(wr1[(size_t)k * 512 + n]);
    } else if (t < S0 + 3 * S1) {
        int idx = t - S0 - 2 * S1;
        int n = idx / 512, k = idx % 512;
        wT2[idx] = __float2bfloat16(wl2[(size_t)k * 128 + n]);
    } else if (t < S0 + 4 * S1) {
        int idx = t - S0 - 3 * S1;
        int n = idx / 512, k = idx % 512;
        wT2[(size_t)(128 + n) * 512 + k] = __float2bfloat16(wr2[(size_t)k * 128 + n]);
    }
}

__device__ void scan_partial_body(int b, const int* __restrict__ deg,
                                  int* __restrict__ bsum, int n) {
    __shared__ int sdata[256];
    int t = threadIdx.x;
    int base = b * SCAN_CHUNK;
    int s = 0;
    for (int i = t; i < SCAN_CHUNK; i += 256) {
        int idx = base + i;
        s += (idx < n) ? deg[idx] : 0;
    }
    sdata[t] = s;
    __syncthreads();
    for (int off = 128; off; off >>= 1) {
        if (t < off) sdata[t] += sdata[t + off];
        __syncthreads();
    }
    if (t == 0) bsum[b] = sdata[0];
}

// scan_final with inline bsum prefix (replaces scan_bsums kernel)
__device__ void scan_final_body(int b, const int* __restrict__ deg,
                                const int* __restrict__ bsum,
                                int* __restrict__ row, int* __restrict__ cursor,
                                int n) {
    __shared__ int tsum[256];
    int t = threadIdx.x;
    int boff = 0;
    #pragma unroll
    for (int i = 0; i < NB_SCAN; ++i) boff += (i < b) ? bsum[i] : 0;
    if (b == 0 && t == 0) {
        int total = 0;
        for (int i = 0; i < NB_SCAN; ++i) total += bsum[i];
        row[n] = total;
    }
    int base = b * SCAN_CHUNK + t * 8;
    int local[8];
    int s = 0;
    #pragma unroll
    for (int k = 0; k < 8; ++k) {
        int idx = base + k;
        int v = (idx < n) ? deg[idx] : 0;
        local[k] = s;
        s += v;
    }
    tsum[t] = s;
    __syncthreads();
    for (int off = 1; off < 256; off <<= 1) {
        int v = 0;
        if (t >= off) v = tsum[t - off];
        __syncthreads();
        if (t >= off) tsum[t] += v;
        __syncthreads();
    }
    int texcl = (t == 0) ? 0 : tsum[t - 1];
    #pragma unroll
    for (int k = 0; k < 8; ++k) {
        int idx = base + k;
        if (idx < n) {
            int v = boff + texcl + local[k];
            row[idx] = v;
            cursor[idx] = v;
        }
    }
}

// ---------------------------------------------------------------------------
// bf16 MFMA GEMM body (128x128 tile), callable from fused kernels.
// A: bf16 or f32 [M,K] (f32 converted during staging), BT bf16 [N,K].
// ---------------------------------------------------------------------------
template<int ACT, typename AT, typename OutT>
__device__ void mfma_gemm_body(
    const AT* __restrict__ A, const __hip_bfloat16* __restrict__ BT,
    const float* __restrict__ bias, OutT* __restrict__ C,
    int M, int K, int N, int rowBlk, int colBlk)
{
    constexpr int LDA = 72;
    __shared__ __align__(16) short As[128 * LDA];
    __shared__ __align__(16) short Bs[128 * LDA];

    const int tid  = threadIdx.x;
    const int lane = tid & 63;
    const int wid  = tid >> 6;
    const int wm   = wid >> 1;
    const int wn   = wid & 1;
    const int fr   = lane & 15;
    const int fk   = (lane >> 4) * 8;

    const int row0 = rowBlk * 128;
    const int col0 = colBlk * 128;

    const short* Bg = (const short*)BT;

    f32x4 acc[4][4] = {};

    for (int k0 = 0; k0 < K; k0 += 64) {
        #pragma unroll
        for (int it = 0; it < 4; ++it) {
            int chunk = it * 256 + tid;
            int r = chunk >> 3, c = chunk & 7;
            int gr = row0 + r;
            short8 v = {0, 0, 0, 0, 0, 0, 0, 0};
            if (gr < M) {
                if constexpr (sizeof(AT) == 2) {
                    v = *(const short8*)((const short*)A + (size_t)gr * K + k0 + c * 8);
                } else {
                    const float* ap = (const float*)A + (size_t)gr * K + k0 + c * 8;
                    float4 a0 = *(const float4*)ap;
                    float4 a1 = *(const float4*)(ap + 4);
                    __hip_bfloat16 h;
                    h = __float2bfloat16(a0.x); v[0] = *(short*)&h;
                    h = __float2bfloat16(a0.y); v[1] = *(short*)&h;
                    h = __float2bfloat16(a0.z); v[2] = *(short*)&h;
                    h = __float2bfloat16(a0.w); v[3] = *(short*)&h;
                    h = __float2bfloat16(a1.x); v[4] = *(short*)&h;
                    h = __float2bfloat16(a1.y); v[5] = *(short*)&h;
                    h = __float2bfloat16(a1.z); v[6] = *(short*)&h;
                    h = __float2bfloat16(a1.w); v[7] = *(short*)&h;
                }
            }
            *(short8*)(&As[r * LDA + c * 8]) = v;
        }
        #pragma unroll
        for (int it = 0; it < 4; ++it) {
            int chunk = it * 256 + tid;
            int n = chunk >> 3, c = chunk & 7;
            short8 v = *(const short8*)(Bg + (size_t)(col0 + n) * K + k0 + c * 8);
            *(short8*)(&Bs[n * LDA + c * 8]) = v;
        }
        __syncthreads();
        #pragma unroll
        for (int kk = 0; kk < 2; ++kk) {
            short8 af[4], bf[4];
            #pragma unroll
            for (int i = 0; i < 4; ++i)
                af[i] = *(const short8*)(&As[(wm * 64 + i * 16 + fr) * LDA + kk * 32 + fk]);
            #pragma unroll
            for (int j = 0; j < 4; ++j)
                bf[j] = *(const short8*)(&Bs[(wn * 64 + j * 16 + fr) * LDA + kk * 32 + fk]);
            #pragma unroll
            for (int i = 0; i < 4; ++i)
                #pragma unroll
                for (int j = 0; j < 4; ++j)
                    acc[i][j] = __builtin_amdgcn_mfma_f32_16x16x32_bf16(af[i], bf[j], acc[i][j], 0, 0, 0);
        }
        __syncthreads();
    }

    const int crow = row0 + wm * 64;
    const int ccol = col0 + wn * 64;
    #pragma unroll
    for (int i = 0; i < 4; ++i) {
        #pragma unroll
        for (int j = 0; j < 4; ++j) {
            int col = ccol + j * 16 + (lane & 15);
            float bv = bias ? bias[col] : 0.0f;
            #pragma unroll
            for (int reg = 0; reg < 4; ++reg) {
                int r = crow + i * 16 + (lane >> 4) * 4 + reg;
                if (r < M) {
                    float v = acc[i][j][reg] + bv;
                    if (ACT == 1) v = (v > 0.0f) ? v : expm1f(v);
                    C[(size_t)r * N + col] = (OutT)v;
                }
            }
        }
    }
}

// ---------------------------------------------------------------------------
// fused setup kernels (block-range specialization)
// ---------------------------------------------------------------------------
#define PREP_BLOCKS 1088   // ceil(278528/256)
#define ZERO_BLOCKS 64

__global__ __launch_bounds__(256) void kA_prep_zero(
    const float* w_in, const float* wl1, const float* wr1,
    const float* wl2, const float* wr2,
    __hip_bfloat16* w_inT, __hip_bfloat16* wT1, __hip_bfloat16* wT2,
    int* deg, int N)
{
    int b = blockIdx.x;
    if (b < PREP_BLOCKS)
        weights_prep_body(b, w_in, wl1, wr1, wl2, wr2, w_inT, wT1, wT2);
    else
        zero_body(b - PREP_BLOCKS, ZERO_BLOCKS, deg, N);
}

__global__ __launch_bounds__(256) void kB_ingemm_deg(
    const float* x, const __hip_bfloat16* w_inT, const float* b_in,
    __hip_bfloat16* h0b, int M,
    const int* dst_arr, int* deg, int E, int N)
{
    int b = blockIdx.x;
    int gemmBlocks = (M + 127) / 128;
    if (b < gemmBlocks)
        mfma_gemm_body<1, float, __hip_bfloat16>(x, w_inT, b_in, h0b, M, F_IN, HID, b, 0);
    else
        deg_body(b - gemmBlocks, dst_arr, deg, E, N);
}

// L1 GEMM half ∥ scan stage. HALF: 0 => rows [0, RSPLIT), scan_partial
//                             1 => rows [RSPLIT, nRow), scan_final
template<int HALF>
__global__ __launch_bounds__(256) void kCD_l1gemm_scan(
    const __hip_bfloat16* h0b, const __hip_bfloat16* wT1,
    __hip_bfloat16* xlr1, int M,
    const int* deg, int* bsum, int* row, int* cursor, int N, int rsplit)
{
    int b = blockIdx.x;
    int nRow = (M + 127) / 128;
    int myRows = (HALF == 0) ? rsplit : (nRow - rsplit);
    int gemmBlocks = myRows * 8;
    if (b < gemmBlocks) {
        int colBlk = b & 7;
        int rowBlk = (b >> 3) + (HALF == 0 ? 0 : rsplit);
        mfma_gemm_body<0, __hip_bfloat16, __hip_bfloat16>(
            h0b, wT1, (const float*)nullptr, xlr1, M, HID, 2 * HC1, rowBlk, colBlk);
    } else {
        int sb = b - gemmBlocks;
        if (HALF == 0) scan_partial_body(sb, deg, bsum, N);
        else           scan_final_body(sb, deg, bsum, row, cursor, N);
    }
}

__global__ __launch_bounds__(256) void scatter_kernel(
    const int* __restrict__ src_arr, const int* __restrict__ dst_arr,
    int* __restrict__ cursor, int* __restrict__ src_sorted, int E, int N)
{
    int e = blockIdx.x * blockDim.x + threadIdx.x;
    if (e >= E) return;
    int s = src_arr[e], d = dst_arr[e];
    if ((unsigned)s >= (unsigned)N) s = 0;
    if ((unsigned)d >= (unsigned)N) d = 0;
    int pos = atomicAdd(&cursor[d], 1);
    src_sorted[pos] = s;
}

__global__ __launch_bounds__(256) void l2gemm_kernel(
    const __hip_bfloat16* out1, const __hip_bfloat16* wT2,
    __hip_bfloat16* xlr2, int M)
{
    mfma_gemm_body<0, __hip_bfloat16, __hip_bfloat16>(
        out1, wT2, (const float*)nullptr, xlr2, M, HC1, 2 * HID, blockIdx.y, blockIdx.x);
}

// ---------------------------------------------------------------------------
// Fused GATv2 layer 1: one wave per dst node, CSR gather, online softmax.
// xlr bf16 [N,1024]: cols 0..511 = xl (gathered, temporal), 512..1023 = xr (NT).
// Branchless exp2-domain online softmax; 2-deep gather prefetch; NT out store.
// ---------------------------------------------------------------------------
__global__ __launch_bounds__(256) void gatv2_l1_fused_kernel(
    const __hip_bfloat16* __restrict__ xlr,
    const int* __restrict__ row, const int* __restrict__ src_sorted,
    const float* __restrict__ att, const float* __restrict__ b1,
    __hip_bfloat16* __restrict__ out1, int N)
{
    int d = blockIdx.x * 4 + (threadIdx.x >> 6);
    if (d >= N) return;
    int lane = threadIdx.x & 63;
    int cbase = lane * 8;
    const short* basep = (const short*)xlr;

    f32x2 xrd2[4], attv2[4];
    {
        uint4 raw = nt_load_u4((const unsigned*)(basep + (size_t)d * 1024 + 512 + cbase));
        const unsigned* u = reinterpret_cast<const unsigned*>(&raw);
        #pragma unroll
        for (int j = 0; j < 4; ++j) xrd2[j] = unpack2(u[j]);
        #pragma unroll
        for (int j = 0; j < 4; ++j) {
            attv2[j].x = att[cbase + 2 * j] * LOG2E;
            attv2[j].y = att[cbase + 2 * j + 1] * LOG2E;
        }
    }

    float m = MNEG;
    float s = 0.0f;
    f32x2 o2[4] = {};

    int rs = row[d], re = row[d + 1];
    int L = re - rs + 1;    // virtual list: 0 = self-loop, 1.. = CSR edges

    // 2-deep prefetched gather
    uint4 r0 = *reinterpret_cast<const uint4*>(basep + (size_t)d * 1024 + cbase);
    uint4 r1 = r0;
    if (L > 1) {
        int sn = src_sorted[rs];
        r1 = *reinterpret_cast<const uint4*>(basep + (size_t)sn * 1024 + cbase);
    }
    for (int p0 = 0; p0 < L; ++p0) {
        uint4 cur = r0;
        r0 = r1;
        if (p0 + 2 < L) {
            int sn = src_sorted[rs + p0 + 1];
            r1 = *reinterpret_cast<const uint4*>(basep + (size_t)sn * 1024 + cbase);
        }
        const unsigned* u = reinterpret_cast<const unsigned*>(&cur);
        f32x2 v2[4];
        #pragma unroll
        for (int j = 0; j < 4; ++j) v2[j] = unpack2(u[j]);

        f32x2 tacc = {0.0f, 0.0f};
        #pragma unroll
        for (int j = 0; j < 4; ++j) {
            f32x2 e = v2[j] + xrd2[j];                       // v_pk_add
            f32x2 e2 = __builtin_elementwise_max(e, e * NEG_SLOPE);  // pk_mul + pk_max
            tacc = __builtin_elementwise_fma(e2, attv2[j], tacc);    // v_pk_fma
        }
        float t = tacc.x + tacc.y;
        t += __shfl_xor(t, 1);
        t += __shfl_xor(t, 2);
        t += __shfl_xor(t, 4);
        t += __shfl_xor(t, 8);
        // branchless online softmax (exp2 domain)
        float mn = fmaxf(m, t);
        float rr = exp2f(m - mn);    // 1 if m unchanged, 0 on first edge
        float p  = exp2f(t - mn);
        s = s * rr + p;
        f32x2 rr2 = {rr, rr}, p2 = {p, p};
        #pragma unroll
        for (int j = 0; j < 4; ++j)
            o2[j] = __builtin_elementwise_fma(p2, v2[j], o2[j] * rr2);
        m = mn;
    }

    float inv = 1.0f / (s + 1e-16f);
    short8 sv;
    #pragma unroll
    for (int j = 0; j < 4; ++j) {
        #pragma unroll
        for (int h = 0; h < 2; ++h) {
            float val = ((h == 0) ? o2[j].x : o2[j].y) * inv + b1[cbase + 2 * j + h];
            val = (val > 0.0f) ? val : expm1f(val);
            __hip_bfloat16 hb = __float2bfloat16(val);
            sv[2 * j + h] = *reinterpret_cast<short*>(&hb);
        }
    }
    // NT store (stream; keep L3 for the gather table)
    unsigned* op = (unsigned*)((short*)out1 + (size_t)d * HC1 + cbase);
    const unsigned* sp = (const unsigned*)&sv;
    __builtin_nontemporal_store(sp[0], op);
    __builtin_nontemporal_store(sp[1], op + 1);
    __builtin_nontemporal_store(sp[2], op + 2);
    __builtin_nontemporal_store(sp[3], op + 3);
}

// ---------------------------------------------------------------------------
// Fused GATv2 layer 2 (H=1) + classifier + log_softmax.
// xlr2 bf16 [N,256]. Four 16-lane groups, each every 4th edge, branchless
// online softmax, 1-deep prefetch, merged via shfl_xor(16/32).
// ---------------------------------------------------------------------------
__global__ __launch_bounds__(256) void gatv2_l2_final_kernel(
    const __hip_bfloat16* __restrict__ xlr2,
    const int* __restrict__ row, const int* __restrict__ src_sorted,
    const float* __restrict__ att2, const float* __restrict__ b2,
    const float* __restrict__ w_out, const float* __restrict__ b_out,
    float* __restrict__ out, int N)
{
    int d = blockIdx.x * 4 + (threadIdx.x >> 6);
    if (d >= N) return;
    int lane = threadIdx.x & 63;
    int g  = lane >> 4;
    int gl = lane & 15;
    int cbase = gl * 8;
    const short* basep = (const short*)xlr2;

    f32x2 xrd2[4], attv2[4];
    {
        uint4 rawx = *reinterpret_cast<const uint4*>(basep + (size_t)d * 256 + 128 + cbase);
        const unsigned* u = reinterpret_cast<const unsigned*>(&rawx);
        #pragma unroll
        for (int j = 0; j < 4; ++j) xrd2[j] = unpack2(u[j]);
        #pragma unroll
        for (int j = 0; j < 4; ++j) {
            attv2[j].x = att2[cbase + 2 * j] * LOG2E;
            attv2[j].y = att2[cbase + 2 * j + 1] * LOG2E;
        }
    }

    float m = MNEG;
    float s = 0.0f;
    f32x2 o2[4] = {};

    int rs = row[d], re = row[d + 1];
    int L = re - rs + 1;

    uint4 r0;
    if (g < L) {
        int sn = (g == 0) ? d : src_sorted[rs + g - 1];
        r0 = *reinterpret_cast<const uint4*>(basep + (size_t)sn * 256 + cbase);
    }
    for (int p0 = g; p0 < L; p0 += 4) {
        uint4 cur = r0;
        if (p0 + 4 < L) {
            int sn = src_sorted[rs + p0 + 3];
            r0 = *reinterpret_cast<const uint4*>(basep + (size_t)sn * 256 + cbase);
        }
        const unsigned* u = reinterpret_cast<const unsigned*>(&cur);
        f32x2 v2[4];
        #pragma unroll
        for (int j = 0; j < 4; ++j) v2[j] = unpack2(u[j]);

        f32x2 tacc = {0.0f, 0.0f};
        #pragma unroll
        for (int j = 0; j < 4; ++j) {
            f32x2 e = v2[j] + xrd2[j];
            f32x2 e2 = __builtin_elementwise_max(e, e * NEG_SLOPE);
            tacc = __builtin_elementwise_fma(e2, attv2[j], tacc);
        }
        float t = tacc.x + tacc.y;
        t += __shfl_xor(t, 1);
        t += __shfl_xor(t, 2);
        t += __shfl_xor(t, 4);
        t += __shfl_xor(t, 8);
        float mn = fmaxf(m, t);
        float rr = exp2f(m - mn);
        float p  = exp2f(t - mn);
        s = s * rr + p;
        f32x2 rr2 = {rr, rr}, p2 = {p, p};
        #pragma unroll
        for (int j = 0; j < 4; ++j)
            o2[j] = __builtin_elementwise_fma(p2, v2[j], o2[j] * rr2);
        m = mn;
    }

    // merge the 4 groups (lane^16, then lane^32); branchless
    #pragma unroll
    for (int off = 16; off <= 32; off <<= 1) {
        float m_o = __shfl_xor(m, off);
        float s_o = __shfl_xor(s, off);
        f32x2 oo[4];
        #pragma unroll
        for (int j = 0; j < 4; ++j) {
            oo[j].x = __shfl_xor(o2[j].x, off);
            oo[j].y = __shfl_xor(o2[j].y, off);
        }
        float mn = fmaxf(m, m_o);
        float a = exp2f(m - mn);
        float b = exp2f(m_o - mn);
        s = s * a + s_o * b;
        f32x2 a2 = {a, a}, b2v = {b, b};
        #pragma unroll
        for (int j = 0; j < 4; ++j)
            o2[j] = o2[j] * a2 + oo[j] * b2v;
        m = mn;
    }

    float inv = 1.0f / (s + 1e-16f);
    float a0 = 0.0f, a1 = 0.0f;
    #pragma unroll
    for (int j = 0; j < 4; ++j) {
        #pragma unroll
        for (int h = 0; h < 2; ++h) {
            int c = cbase + 2 * j + h;
            float val = ((h == 0) ? o2[j].x : o2[j].y) * inv + b2[c];
            val = (val > 0.0f) ? val : expm1f(val);
            a0 = fmaf(val, w_out[c * 2 + 0], a0);
            a1 = fmaf(val, w_out[c * 2 + 1], a1);
        }
    }
    #pragma unroll
    for (int off = 1; off <= 8; off <<= 1) {
        a0 += __shfl_xor(a0, off);
        a1 += __shfl_xor(a1, off);
    }
    if (lane == 0) {
        float z0 = a0 + b_out[0];
        float z1 = a1 + b_out[1];
        float mx = fmaxf(z0, z1);
        float lse = mx + logf(__expf(z0 - mx) + __expf(z1 - mx));
        out[(size_t)d * CLASSES + 0] = z0 - lse;
        out[(size_t)d * CLASSES + 1] = z1 - lse;
    }
}

// ---------------------------------------------------------------------------
// launch — 8 dispatches
// ---------------------------------------------------------------------------
extern "C" void kernel_launch(void* const* d_in, const int* in_sizes, int n_in,
                              void* d_out, int out_size, void* d_ws, size_t ws_size,
                              hipStream_t stream)
{
    const float* x     = (const float*)d_in[0];
    const int*   eidx  = (const int*)d_in[1];
    const float* w_in  = (const float*)d_in[2];
    const float* b_in  = (const float*)d_in[3];
    const float* wl1   = (const float*)d_in[4];
    const float* wr1   = (const float*)d_in[5];
    const float* att1  = (const float*)d_in[6];
    const float* b1    = (const float*)d_in[7];
    const float* wl2   = (const float*)d_in[8];
    const float* wr2   = (const float*)d_in[9];
    const float* att2  = (const float*)d_in[10];
    const float* b2    = (const float*)d_in[11];
    const float* w_out = (const float*)d_in[12];
    const float* b_out = (const float*)d_in[13];
    float* out = (float*)d_out;

    const int N = in_sizes[0] / F_IN;      // 50000
    const int E = in_sizes[1] / 2;         // 800000
    const int* src_arr = eidx;
    const int* dst_arr = eidx + E;

    // ---- workspace layout (peak ~172 MB) ----
    size_t off = 0;
    auto alloc = [&](size_t bytes) -> char* {
        char* ptr = (char*)d_ws + off;
        off += (bytes + 255) & ~(size_t)255;
        return ptr;
    };
    int* row        = (int*)alloc((size_t)(N + 1) * 4);
    int* cursor     = (int*)alloc((size_t)N * 4);
    int* deg        = (int*)alloc((size_t)N * 4);
    int* bsum       = (int*)alloc(64 * 4);
    int* src_sorted = (int*)alloc((size_t)E * 4);
    __hip_bfloat16* w_inT = (__hip_bfloat16*)alloc((size_t)F_IN * HID * 2);
    __hip_bfloat16* wT1   = (__hip_bfloat16*)alloc((size_t)2 * HC1 * HID * 2);  // [1024][128]
    __hip_bfloat16* wT2   = (__hip_bfloat16*)alloc((size_t)2 * HID * HC1 * 2);  // [256][512]
    __hip_bfloat16* h0b   = (__hip_bfloat16*)alloc((size_t)N * HID * 2);
    __hip_bfloat16* xlr1  = (__hip_bfloat16*)alloc((size_t)N * 2 * HC1 * 2);    // [N][1024]
    __hip_bfloat16* out1  = (__hip_bfloat16*)alloc((size_t)N * HC1 * 2);

    __hip_bfloat16* xlr2 = xlr1;   // [N][256] overlays xlr1 (dead after fused L1)

    dim3 blk(256);
    const int nRowBlk = (N + 127) / 128;       // 391
    const int rsplit  = (nRowBlk + 1) / 2;     // 196
    const int degBlocks = (E + 255) / 256;     // 3125

    // K_A: weights prep ∥ zero(deg)
    hipLaunchKernelGGL(kA_prep_zero, dim3(PREP_BLOCKS + ZERO_BLOCKS), blk, 0, stream,
                       w_in, wl1, wr1, wl2, wr2, w_inT, wT1, wT2, deg, N);
    // K_B: input GEMM ∥ deg histogram
    hipLaunchKernelGGL(kB_ingemm_deg, dim3(nRowBlk + degBlocks), blk, 0, stream,
                       x, w_inT, b_in, h0b, N, dst_arr, deg, E, N);
    // K_C: L1 GEMM half1 ∥ scan_partial
    hipLaunchKernelGGL((kCD_l1gemm_scan<0>), dim3(rsplit * 8 + NB_SCAN), blk, 0, stream,
                       h0b, wT1, xlr1, N, deg, bsum, row, cursor, N, rsplit);
    // K_D: L1 GEMM half2 ∥ scan_final (inline bsum prefix)
    hipLaunchKernelGGL((kCD_l1gemm_scan<1>), dim3((nRowBlk - rsplit) * 8 + NB_SCAN), blk, 0, stream,
                       h0b, wT1, xlr1, N, deg, bsum, row, cursor, N, rsplit);
    // K_E: scatter
    hipLaunchKernelGGL(scatter_kernel, dim3(degBlocks), blk, 0, stream,
                       src_arr, dst_arr, cursor, src_sorted, E, N);
    // fused layer 1
    hipLaunchKernelGGL(gatv2_l1_fused_kernel, dim3((N + 3) / 4), blk, 0, stream,
                       xlr1, row, src_sorted, att1, b1, out1, N);
    // L2 GEMM (combined wl2|wr2 -> xlr2 [N][256])
    {
        dim3 grid(2 * HID / 128, nRowBlk);
        hipLaunchKernelGGL(l2gemm_kernel, grid, blk, 0, stream, out1, wT2, xlr2, N);
    }
    // fused layer 2 + classifier + log_softmax
    hipLaunchKernelGGL(gatv2_l2_final_kernel, dim3((N + 3) / 4), blk, 0, stream,
                       xlr2, row, src_sorted, att2, b2, w_out, b_out, out, N);
}

// Round 12
// 551.119 us; speedup vs baseline: 1.1100x; 1.1100x over previous
//
#include <hip/hip_runtime.h>
#include <hip/hip_bf16.h>
#include <math.h>

#define F_IN   128
#define HID    128
#define HEADS  4
#define HC1    (HEADS*HID)   // 512
#define CLASSES 2
#define NEG_SLOPE 0.2f
#define LOG2E 1.44269504088896340736f
#define MNEG  -3.0e38f

#define SCAN_CHUNK 2048

typedef __attribute__((ext_vector_type(8))) short short8;
typedef __attribute__((ext_vector_type(4))) float f32x4;
typedef __attribute__((ext_vector_type(2))) float f32x2;

__device__ __forceinline__ f32x2 unpack2(unsigned u) {
    f32x2 r;
    r.x = __uint_as_float(u << 16);
    r.y = __uint_as_float(u & 0xffff0000u);
    return r;
}

// ---------------------------------------------------------------------------
// CSR build: deg histogram -> exclusive scan -> scatter src ids by dst
// ---------------------------------------------------------------------------
__global__ void zero_int_kernel(int* __restrict__ p, int n) {
    int i = blockIdx.x * blockDim.x + threadIdx.x;
    int stride = gridDim.x * blockDim.x;
    for (; i < n; i += stride) p[i] = 0;
}

__global__ void deg_kernel(const int* __restrict__ dst_arr, int* __restrict__ deg,
                           int E, int N) {
    int e = blockIdx.x * blockDim.x + threadIdx.x;
    if (e >= E) return;
    int d = dst_arr[e];
    if ((unsigned)d >= (unsigned)N) d = 0;
    atomicAdd(&deg[d], 1);
}

__global__ void scan_partial_kernel(const int* __restrict__ deg, int* __restrict__ bsum, int n) {
    __shared__ int sdata[256];
    int b = blockIdx.x, t = threadIdx.x;
    int base = b * SCAN_CHUNK;
    int s = 0;
    for (int i = t; i < SCAN_CHUNK; i += 256) {
        int idx = base + i;
        s += (idx < n) ? deg[idx] : 0;
    }
    sdata[t] = s;
    __syncthreads();
    for (int off = 128; off; off >>= 1) {
        if (t < off) sdata[t] += sdata[t + off];
        __syncthreads();
    }
    if (t == 0) bsum[b] = sdata[0];
}

__global__ void scan_bsums_kernel(int* __restrict__ bsum, int nb, int* __restrict__ row, int n) {
    if (blockIdx.x == 0 && threadIdx.x == 0) {
        int acc = 0;
        for (int i = 0; i < nb; ++i) { int v = bsum[i]; bsum[i] = acc; acc += v; }
        row[n] = acc;
    }
}

__global__ void scan_final_kernel(const int* __restrict__ deg, const int* __restrict__ bsum,
                                  int* __restrict__ row, int* __restrict__ cursor, int n) {
    __shared__ int tsum[256];
    int b = blockIdx.x, t = threadIdx.x;
    int base = b * SCAN_CHUNK + t * 8;
    int local[8];
    int s = 0;
    #pragma unroll
    for (int k = 0; k < 8; ++k) {
        int idx = base + k;
        int v = (idx < n) ? deg[idx] : 0;
        local[k] = s;
        s += v;
    }
    tsum[t] = s;
    __syncthreads();
    for (int off = 1; off < 256; off <<= 1) {
        int v = 0;
        if (t >= off) v = tsum[t - off];
        __syncthreads();
        if (t >= off) tsum[t] += v;
        __syncthreads();
    }
    int texcl = (t == 0) ? 0 : tsum[t - 1];
    int boff = bsum[b];
    #pragma unroll
    for (int k = 0; k < 8; ++k) {
        int idx = base + k;
        if (idx < n) {
            int v = boff + texcl + local[k];
            row[idx] = v;
            cursor[idx] = v;
        }
    }
}

__global__ void scatter_kernel(const int* __restrict__ src_arr, const int* __restrict__ dst_arr,
                               int* __restrict__ cursor, int* __restrict__ src_sorted,
                               int E, int N) {
    int e = blockIdx.x * blockDim.x + threadIdx.x;
    if (e >= E) return;
    int s = src_arr[e], d = dst_arr[e];
    if ((unsigned)s >= (unsigned)N) s = 0;
    if ((unsigned)d >= (unsigned)N) d = 0;
    int pos = atomicAdd(&cursor[d], 1);
    src_sorted[pos] = s;
}

// ---------------------------------------------------------------------------
// fused weight prep: transpose+bf16 all 5 weight matrices into combined
// layouts: w_inT [128][128]; wT1 [1024][128] (wl1|wr1); wT2 [256][512] (wl2|wr2)
// ---------------------------------------------------------------------------
__global__ void weights_prep_kernel(
    const float* __restrict__ w_in, const float* __restrict__ wl1,
    const float* __restrict__ wr1, const float* __restrict__ wl2,
    const float* __restrict__ wr2,
    __hip_bfloat16* __restrict__ w_inT, __hip_bfloat16* __restrict__ wT1,
    __hip_bfloat16* __restrict__ wT2)
{
    int t = blockIdx.x * blockDim.x + threadIdx.x;
    const int S0 = 128 * 128, S1 = 128 * 512;
    if (t < S0) {
        int n = t / 128, k = t % 128;
        w_inT[t] = __float2bfloat16(w_in[(size_t)k * 128 + n]);
    } else if (t < S0 + S1) {
        int idx = t - S0;
        int n = idx / 128, k = idx % 128;
        wT1[idx] = __float2bfloat16(wl1[(size_t)k * 512 + n]);
    } else if (t < S0 + 2 * S1) {
        int idx = t - S0 - S1;
        int n = idx / 128, k = idx % 128;
        wT1[(size_t)(512 + n) * 128 + k] = __float2bfloat16(wr1[(size_t)k * 512 + n]);
    } else if (t < S0 + 3 * S1) {
        int idx = t - S0 - 2 * S1;
        int n = idx / 512, k = idx % 512;
        wT2[idx] = __float2bfloat16(wl2[(size_t)k * 128 + n]);
    } else if (t < S0 + 4 * S1) {
        int idx = t - S0 - 3 * S1;
        int n = idx / 512, k = idx % 512;
        wT2[(size_t)(128 + n) * 512 + k] = __float2bfloat16(wr2[(size_t)k * 128 + n]);
    }
}

// ---------------------------------------------------------------------------
// Merged input+L1 transform (persistent-A):
// Phase 1: h = elu(x @ w_inT^T + b_in) computed into LDS (bf16, [128][136]).
// Phase 2: 4 col-tiles of xlr1 = h @ wT1^T using the LDS h-tile as A.
// grid = (2, nRowBlk): blockIdx.x selects col-tiles {0..3} or {4..7}.
// Eliminates the h0b global round-trip (write + 8x re-read).
// ---------------------------------------------------------------------------
__global__ __launch_bounds__(256) void l1_merged_kernel(
    const float* __restrict__ x, const __hip_bfloat16* __restrict__ w_inT,
    const float* __restrict__ b_in, const __hip_bfloat16* __restrict__ wT1,
    __hip_bfloat16* __restrict__ xlr1, int M)
{
    constexpr int LDA = 136, LDB = 72;
    __shared__ __align__(16) short As[128 * LDA];   // h tile (phase-2 A)
    __shared__ __align__(16) short Bs[128 * LDB];   // x / wT1 staging
    short* Ws = As;                                  // w_inT staging aliases As (dead before h-write)

    const int tid  = threadIdx.x;
    const int lane = tid & 63;
    const int wid  = tid >> 6;
    const int wm   = wid >> 1;
    const int wn   = wid & 1;
    const int fr   = lane & 15;
    const int fk   = (lane >> 4) * 8;
    const int row0 = blockIdx.y * 128;

    // ---- phase 1: h-tile = elu(x @ w_inT + b_in) ----
    {
        f32x4 acc[4][4] = {};
        for (int k0 = 0; k0 < 128; k0 += 64) {
            __syncthreads();
            // stage x chunk (f32 -> bf16): 128 rows x 64 k -> Bs
            #pragma unroll
            for (int it = 0; it < 4; ++it) {
                int chunk = it * 256 + tid;
                int r = chunk >> 3, c = chunk & 7;
                int gr = row0 + r;
                short8 v = {0, 0, 0, 0, 0, 0, 0, 0};
                if (gr < M) {
                    const float* ap = x + (size_t)gr * 128 + k0 + c * 8;
                    float4 a0 = *(const float4*)ap;
                    float4 a1 = *(const float4*)(ap + 4);
                    __hip_bfloat16 h;
                    h = __float2bfloat16(a0.x); v[0] = *(short*)&h;
                    h = __float2bfloat16(a0.y); v[1] = *(short*)&h;
                    h = __float2bfloat16(a0.z); v[2] = *(short*)&h;
                    h = __float2bfloat16(a0.w); v[3] = *(short*)&h;
                    h = __float2bfloat16(a1.x); v[4] = *(short*)&h;
                    h = __float2bfloat16(a1.y); v[5] = *(short*)&h;
                    h = __float2bfloat16(a1.z); v[6] = *(short*)&h;
                    h = __float2bfloat16(a1.w); v[7] = *(short*)&h;
                }
                *(short8*)(&Bs[r * LDB + c * 8]) = v;
            }
            // stage w_inT chunk: 128 n x 64 k -> Ws (=As region)
            #pragma unroll
            for (int it = 0; it < 4; ++it) {
                int chunk = it * 256 + tid;
                int n = chunk >> 3, c = chunk & 7;
                short8 v = *(const short8*)((const short*)w_inT + (size_t)n * 128 + k0 + c * 8);
                *(short8*)(&Ws[n * LDB + c * 8]) = v;
            }
            __syncthreads();
            #pragma unroll
            for (int kk = 0; kk < 2; ++kk) {
                short8 af[4], bf[4];
                #pragma unroll
                for (int i = 0; i < 4; ++i)
                    af[i] = *(const short8*)(&Bs[(wm * 64 + i * 16 + fr) * LDB + kk * 32 + fk]);
                #pragma unroll
                for (int j = 0; j < 4; ++j)
                    bf[j] = *(const short8*)(&Ws[(wn * 64 + j * 16 + fr) * LDB + kk * 32 + fk]);
                #pragma unroll
                for (int i = 0; i < 4; ++i)
                    #pragma unroll
                    for (int j = 0; j < 4; ++j)
                        acc[i][j] = __builtin_amdgcn_mfma_f32_16x16x32_bf16(af[i], bf[j], acc[i][j], 0, 0, 0);
            }
        }
        __syncthreads();   // all Ws reads done; As region free for h
        // write h = elu(acc + b_in) into As (bf16): row = wm*64+i*16+(lane>>4)*4+reg, col = wn*64+j*16+fr
        #pragma unroll
        for (int i = 0; i < 4; ++i) {
            #pragma unroll
            for (int j = 0; j < 4; ++j) {
                int col = wn * 64 + j * 16 + fr;
                float bv = b_in[col];
                #pragma unroll
                for (int reg = 0; reg < 4; ++reg) {
                    int r = wm * 64 + i * 16 + (lane >> 4) * 4 + reg;
                    float v = acc[i][j][reg] + bv;
                    v = (v > 0.0f) ? v : expm1f(v);
                    __hip_bfloat16 hb = __float2bfloat16(v);
                    As[r * LDA + col] = *reinterpret_cast<short*>(&hb);
                }
            }
        }
        __syncthreads();
    }

    // ---- phase 2: 4 col-tiles of xlr1 = h @ wT1^T ----
    const int colBase = blockIdx.x * 4;
    for (int ct = 0; ct < 4; ++ct) {
        const int col0 = (colBase + ct) * 128;
        f32x4 acc[4][4] = {};
        for (int k0 = 0; k0 < 128; k0 += 64) {
            __syncthreads();   // Bs WAR
            #pragma unroll
            for (int it = 0; it < 4; ++it) {
                int chunk = it * 256 + tid;
                int n = chunk >> 3, c = chunk & 7;
                short8 v = *(const short8*)((const short*)wT1 + (size_t)(col0 + n) * 128 + k0 + c * 8);
                *(short8*)(&Bs[n * LDB + c * 8]) = v;
            }
            __syncthreads();
            #pragma unroll
            for (int kk = 0; kk < 2; ++kk) {
                short8 af[4], bf[4];
                #pragma unroll
                for (int i = 0; i < 4; ++i)
                    af[i] = *(const short8*)(&As[(wm * 64 + i * 16 + fr) * LDA + k0 + kk * 32 + fk]);
                #pragma unroll
                for (int j = 0; j < 4; ++j)
                    bf[j] = *(const short8*)(&Bs[(wn * 64 + j * 16 + fr) * LDB + kk * 32 + fk]);
                #pragma unroll
                for (int i = 0; i < 4; ++i)
                    #pragma unroll
                    for (int j = 0; j < 4; ++j)
                        acc[i][j] = __builtin_amdgcn_mfma_f32_16x16x32_bf16(af[i], bf[j], acc[i][j], 0, 0, 0);
            }
        }
        const int crow = row0 + wm * 64;
        const int ccol = col0 + wn * 64;
        #pragma unroll
        for (int i = 0; i < 4; ++i) {
            #pragma unroll
            for (int j = 0; j < 4; ++j) {
                int col = ccol + j * 16 + fr;
                #pragma unroll
                for (int reg = 0; reg < 4; ++reg) {
                    int r = crow + i * 16 + (lane >> 4) * 4 + reg;
                    if (r < M) xlr1[(size_t)r * 1024 + col] = (__hip_bfloat16)acc[i][j][reg];
                }
            }
        }
    }
}

// ---------------------------------------------------------------------------
// bf16 MFMA GEMM (128x128 tile) — used for the L2 transform.
// ---------------------------------------------------------------------------
template<int ACT, typename OutT>
__global__ __launch_bounds__(256) void mfma_gemm_kernel(
    const __hip_bfloat16* __restrict__ A,
    const __hip_bfloat16* __restrict__ BT,
    const float* __restrict__ bias,
    OutT* __restrict__ C,
    int M, int K, int N)
{
    constexpr int LDA = 72;
    __shared__ __align__(16) short As[128 * LDA];
    __shared__ __align__(16) short Bs[128 * LDA];

    const int tid  = threadIdx.x;
    const int lane = tid & 63;
    const int wid  = tid >> 6;
    const int wm   = wid >> 1;
    const int wn   = wid & 1;
    const int fr   = lane & 15;
    const int fk   = (lane >> 4) * 8;

    const int row0 = blockIdx.y * 128;
    const int col0 = blockIdx.x * 128;

    const short* Ag = (const short*)A;
    const short* Bg = (const short*)BT;

    f32x4 acc[4][4] = {};

    for (int k0 = 0; k0 < K; k0 += 64) {
        #pragma unroll
        for (int it = 0; it < 4; ++it) {
            int chunk = it * 256 + tid;
            int r = chunk >> 3, c = chunk & 7;
            int gr = row0 + r;
            short8 v = {0, 0, 0, 0, 0, 0, 0, 0};
            if (gr < M) v = *(const short8*)(Ag + (size_t)gr * K + k0 + c * 8);
            *(short8*)(&As[r * LDA + c * 8]) = v;
        }
        #pragma unroll
        for (int it = 0; it < 4; ++it) {
            int chunk = it * 256 + tid;
            int n = chunk >> 3, c = chunk & 7;
            short8 v = *(const short8*)(Bg + (size_t)(col0 + n) * K + k0 + c * 8);
            *(short8*)(&Bs[n * LDA + c * 8]) = v;
        }
        __syncthreads();
        #pragma unroll
        for (int kk = 0; kk < 2; ++kk) {
            short8 af[4], bf[4];
            #pragma unroll
            for (int i = 0; i < 4; ++i)
                af[i] = *(const short8*)(&As[(wm * 64 + i * 16 + fr) * LDA + kk * 32 + fk]);
            #pragma unroll
            for (int j = 0; j < 4; ++j)
                bf[j] = *(const short8*)(&Bs[(wn * 64 + j * 16 + fr) * LDA + kk * 32 + fk]);
            #pragma unroll
            for (int i = 0; i < 4; ++i)
                #pragma unroll
                for (int j = 0; j < 4; ++j)
                    acc[i][j] = __builtin_amdgcn_mfma_f32_16x16x32_bf16(af[i], bf[j], acc[i][j], 0, 0, 0);
        }
        __syncthreads();
    }

    const int crow = row0 + wm * 64;
    const int ccol = col0 + wn * 64;
    #pragma unroll
    for (int i = 0; i < 4; ++i) {
        #pragma unroll
        for (int j = 0; j < 4; ++j) {
            int col = ccol + j * 16 + (lane & 15);
            float bv = bias ? bias[col] : 0.0f;
            #pragma unroll
            for (int reg = 0; reg < 4; ++reg) {
                int r = crow + i * 16 + (lane >> 4) * 4 + reg;
                if (r < M) {
                    float v = acc[i][j][reg] + bv;
                    if (ACT == 1) v = (v > 0.0f) ? v : expm1f(v);
                    C[(size_t)r * N + col] = (OutT)v;
                }
            }
        }
    }
}

// ---------------------------------------------------------------------------
// Fused GATv2 layer 1 (round-9 verified version): one wave per dst node,
// CSR gather, branchy online softmax in exp2 domain, 1-deep prefetch,
// f32x2 pk arithmetic. xlr bf16 [N,1024]: 0..511 = xl, 512..1023 = xr.
// ---------------------------------------------------------------------------
__global__ __launch_bounds__(256) void gatv2_l1_fused_kernel(
    const __hip_bfloat16* __restrict__ xlr,
    const int* __restrict__ row, const int* __restrict__ src_sorted,
    const float* __restrict__ att, const float* __restrict__ b1,
    __hip_bfloat16* __restrict__ out1, int N)
{
    int d = blockIdx.x * 4 + (threadIdx.x >> 6);
    if (d >= N) return;
    int lane = threadIdx.x & 63;
    int cbase = lane * 8;
    const short* basep = (const short*)xlr;

    f32x2 xrd2[4], attv2[4];
    {
        uint4 raw = *reinterpret_cast<const uint4*>(basep + (size_t)d * 1024 + 512 + cbase);
        const unsigned* u = reinterpret_cast<const unsigned*>(&raw);
        #pragma unroll
        for (int j = 0; j < 4; ++j) xrd2[j] = unpack2(u[j]);
        #pragma unroll
        for (int j = 0; j < 4; ++j) {
            attv2[j].x = att[cbase + 2 * j] * LOG2E;
            attv2[j].y = att[cbase + 2 * j + 1] * LOG2E;
        }
    }

    float m = MNEG;
    float s = 0.0f;
    f32x2 o2[4] = {};

    int rs = row[d], re = row[d + 1];

    uint4 raw = *reinterpret_cast<const uint4*>(basep + (size_t)d * 1024 + cbase);
    for (int it = rs - 1; it < re; ++it) {
        uint4 cur = raw;
        if (it + 1 < re) {
            int sn = src_sorted[it + 1];
            raw = *reinterpret_cast<const uint4*>(basep + (size_t)sn * 1024 + cbase);
        }
        const unsigned* u = reinterpret_cast<const unsigned*>(&cur);
        f32x2 v2[4];
        #pragma unroll
        for (int j = 0; j < 4; ++j) v2[j] = unpack2(u[j]);

        f32x2 tacc = {0.0f, 0.0f};
        #pragma unroll
        for (int j = 0; j < 4; ++j) {
            f32x2 e = v2[j] + xrd2[j];
            f32x2 ne = e * NEG_SLOPE;
            e.x = fmaxf(e.x, ne.x);
            e.y = fmaxf(e.y, ne.y);
            tacc = __builtin_elementwise_fma(e, attv2[j], tacc);
        }
        float t = tacc.x + tacc.y;
        t += __shfl_xor(t, 1);
        t += __shfl_xor(t, 2);
        t += __shfl_xor(t, 4);
        t += __shfl_xor(t, 8);
        if (t > m) {
            float r = exp2f(m - t);
            s *= r;
            f32x2 r2 = {r, r};
            #pragma unroll
            for (int j = 0; j < 4; ++j) o2[j] *= r2;
            m = t;
        }
        float p = exp2f(t - m);
        s += p;
        f32x2 p2 = {p, p};
        #pragma unroll
        for (int j = 0; j < 4; ++j) o2[j] = __builtin_elementwise_fma(p2, v2[j], o2[j]);
    }

    float inv = 1.0f / (s + 1e-16f);
    short8 sv;
    #pragma unroll
    for (int j = 0; j < 4; ++j) {
        #pragma unroll
        for (int h = 0; h < 2; ++h) {
            float val = ((h == 0) ? o2[j].x : o2[j].y) * inv + b1[cbase + 2 * j + h];
            val = (val > 0.0f) ? val : expm1f(val);
            __hip_bfloat16 hb = __float2bfloat16(val);
            sv[2 * j + h] = *reinterpret_cast<short*>(&hb);
        }
    }
    *(short8*)((short*)out1 + (size_t)d * HC1 + cbase) = sv;
}

// ---------------------------------------------------------------------------
// Fused GATv2 layer 2 (round-9 verified version): 4x16-lane groups,
// branchy online softmax, merged via shfl_xor(16/32). Writes d_out [N,2].
// ---------------------------------------------------------------------------
__global__ __launch_bounds__(256) void gatv2_l2_final_kernel(
    const __hip_bfloat16* __restrict__ xlr2,
    const int* __restrict__ row, const int* __restrict__ src_sorted,
    const float* __restrict__ att2, const float* __restrict__ b2,
    const float* __restrict__ w_out, const float* __restrict__ b_out,
    float* __restrict__ out, int N)
{
    int d = blockIdx.x * 4 + (threadIdx.x >> 6);
    if (d >= N) return;
    int lane = threadIdx.x & 63;
    int g  = lane >> 4;
    int gl = lane & 15;
    int cbase = gl * 8;
    const short* basep = (const short*)xlr2;

    f32x2 xrd2[4], attv2[4];
    {
        uint4 rawx = *reinterpret_cast<const uint4*>(basep + (size_t)d * 256 + 128 + cbase);
        const unsigned* u = reinterpret_cast<const unsigned*>(&rawx);
        #pragma unroll
        for (int j = 0; j < 4; ++j) xrd2[j] = unpack2(u[j]);
        #pragma unroll
        for (int j = 0; j < 4; ++j) {
            attv2[j].x = att2[cbase + 2 * j] * LOG2E;
            attv2[j].y = att2[cbase + 2 * j + 1] * LOG2E;
        }
    }

    float m = MNEG;
    float s = 0.0f;
    f32x2 o2[4] = {};

    int rs = row[d], re = row[d + 1];
    int L = re - rs + 1;   // virtual list: position 0 = self-loop, 1.. = CSR

    for (int p0 = g; p0 < L; p0 += 4) {
        int srcn = (p0 == 0) ? d : src_sorted[rs + p0 - 1];
        uint4 cur = *reinterpret_cast<const uint4*>(basep + (size_t)srcn * 256 + cbase);
        const unsigned* u = reinterpret_cast<const unsigned*>(&cur);
        f32x2 v2[4];
        #pragma unroll
        for (int j = 0; j < 4; ++j) v2[j] = unpack2(u[j]);

        f32x2 tacc = {0.0f, 0.0f};
        #pragma unroll
        for (int j = 0; j < 4; ++j) {
            f32x2 e = v2[j] + xrd2[j];
            f32x2 ne = e * NEG_SLOPE;
            e.x = fmaxf(e.x, ne.x);
            e.y = fmaxf(e.y, ne.y);
            tacc = __builtin_elementwise_fma(e, attv2[j], tacc);
        }
        float t = tacc.x + tacc.y;
        t += __shfl_xor(t, 1);
        t += __shfl_xor(t, 2);
        t += __shfl_xor(t, 4);
        t += __shfl_xor(t, 8);
        if (t > m) {
            float r = exp2f(m - t);
            s *= r;
            f32x2 r2 = {r, r};
            #pragma unroll
            for (int j = 0; j < 4; ++j) o2[j] *= r2;
            m = t;
        }
        float p = exp2f(t - m);
        s += p;
        f32x2 p2 = {p, p};
        #pragma unroll
        for (int j = 0; j < 4; ++j) o2[j] = __builtin_elementwise_fma(p2, v2[j], o2[j]);
    }

    // merge the 4 groups (lane^16, then lane^32); branchless (m init = -3e38)
    #pragma unroll
    for (int off = 16; off <= 32; off <<= 1) {
        float m_o = __shfl_xor(m, off);
        float s_o = __shfl_xor(s, off);
        f32x2 oo[4];
        #pragma unroll
        for (int j = 0; j < 4; ++j) {
            oo[j].x = __shfl_xor(o2[j].x, off);
            oo[j].y = __shfl_xor(o2[j].y, off);
        }
        float mn = fmaxf(m, m_o);
        float a = exp2f(m - mn);
        float b = exp2f(m_o - mn);
        s = s * a + s_o * b;
        f32x2 a2 = {a, a}, b2v = {b, b};
        #pragma unroll
        for (int j = 0; j < 4; ++j)
            o2[j] = o2[j] * a2 + oo[j] * b2v;
        m = mn;
    }

    float inv = 1.0f / (s + 1e-16f);
    float a0 = 0.0f, a1 = 0.0f;
    #pragma unroll
    for (int j = 0; j < 4; ++j) {
        #pragma unroll
        for (int h = 0; h < 2; ++h) {
            int c = cbase + 2 * j + h;
            float val = ((h == 0) ? o2[j].x : o2[j].y) * inv + b2[c];
            val = (val > 0.0f) ? val : expm1f(val);
            a0 = fmaf(val, w_out[c * 2 + 0], a0);
            a1 = fmaf(val, w_out[c * 2 + 1], a1);
        }
    }
    #pragma unroll
    for (int off = 1; off <= 8; off <<= 1) {
        a0 += __shfl_xor(a0, off);
        a1 += __shfl_xor(a1, off);
    }
    if (lane == 0) {
        float z0 = a0 + b_out[0];
        float z1 = a1 + b_out[1];
        float mx = fmaxf(z0, z1);
        float lse = mx + logf(__expf(z0 - mx) + __expf(z1 - mx));
        out[(size_t)d * CLASSES + 0] = z0 - lse;
        out[(size_t)d * CLASSES + 1] = z1 - lse;
    }
}

// ---------------------------------------------------------------------------
// launch — 11 dispatches
// ---------------------------------------------------------------------------
extern "C" void kernel_launch(void* const* d_in, const int* in_sizes, int n_in,
                              void* d_out, int out_size, void* d_ws, size_t ws_size,
                              hipStream_t stream)
{
    const float* x     = (const float*)d_in[0];
    const int*   eidx  = (const int*)d_in[1];
    const float* w_in  = (const float*)d_in[2];
    const float* b_in  = (const float*)d_in[3];
    const float* wl1   = (const float*)d_in[4];
    const float* wr1   = (const float*)d_in[5];
    const float* att1  = (const float*)d_in[6];
    const float* b1    = (const float*)d_in[7];
    const float* wl2   = (const float*)d_in[8];
    const float* wr2   = (const float*)d_in[9];
    const float* att2  = (const float*)d_in[10];
    const float* b2    = (const float*)d_in[11];
    const float* w_out = (const float*)d_in[12];
    const float* b_out = (const float*)d_in[13];
    float* out = (float*)d_out;

    const int N = in_sizes[0] / F_IN;      // 50000
    const int E = in_sizes[1] / 2;         // 800000
    const int* src_arr = eidx;
    const int* dst_arr = eidx + E;

    // ---- workspace layout (peak ~160 MB) ----
    size_t off = 0;
    auto alloc = [&](size_t bytes) -> char* {
        char* ptr = (char*)d_ws + off;
        off += (bytes + 255) & ~(size_t)255;
        return ptr;
    };
    int* row        = (int*)alloc((size_t)(N + 1) * 4);
    int* cursor     = (int*)alloc((size_t)N * 4);
    int* deg        = (int*)alloc((size_t)N * 4);
    int* bsum       = (int*)alloc(64 * 4);
    int* src_sorted = (int*)alloc((size_t)E * 4);
    __hip_bfloat16* w_inT = (__hip_bfloat16*)alloc((size_t)F_IN * HID * 2);
    __hip_bfloat16* wT1   = (__hip_bfloat16*)alloc((size_t)2 * HC1 * HID * 2);  // [1024][128]
    __hip_bfloat16* wT2   = (__hip_bfloat16*)alloc((size_t)2 * HID * HC1 * 2);  // [256][512]
    __hip_bfloat16* xlr1  = (__hip_bfloat16*)alloc((size_t)N * 2 * HC1 * 2);    // [N][1024]
    __hip_bfloat16* out1  = (__hip_bfloat16*)alloc((size_t)N * HC1 * 2);

    __hip_bfloat16* xlr2 = xlr1;   // [N][256] overlays xlr1 (dead after fused L1)

    dim3 blk(256);
    const int NB_SCAN = (N + SCAN_CHUNK - 1) / SCAN_CHUNK;
    const int nRowBlk = (N + 127) / 128;       // 391

    // ---- CSR build ----
    hipLaunchKernelGGL(zero_int_kernel, dim3(64), blk, 0, stream, deg, N);
    hipLaunchKernelGGL(deg_kernel, dim3((E + 255) / 256), blk, 0, stream, dst_arr, deg, E, N);
    hipLaunchKernelGGL(scan_partial_kernel, dim3(NB_SCAN), blk, 0, stream, deg, bsum, N);
    hipLaunchKernelGGL(scan_bsums_kernel, dim3(1), blk, 0, stream, bsum, NB_SCAN, row, N);
    hipLaunchKernelGGL(scan_final_kernel, dim3(NB_SCAN), blk, 0, stream, deg, bsum, row, cursor, N);
    hipLaunchKernelGGL(scatter_kernel, dim3((E + 255) / 256), blk, 0, stream,
                       src_arr, dst_arr, cursor, src_sorted, E, N);

    // ---- weight prep (single kernel, combined layouts) ----
    {
        int total = 128 * 128 + 4 * 128 * 512;
        hipLaunchKernelGGL(weights_prep_kernel, dim3((total + 255) / 256), blk, 0, stream,
                           w_in, wl1, wr1, wl2, wr2, w_inT, wT1, wT2);
    }
    // ---- merged input+L1 transform: x -> h (LDS) -> xlr1 [N][1024] ----
    {
        dim3 grid(2, nRowBlk);
        hipLaunchKernelGGL(l1_merged_kernel, grid, blk, 0, stream,
                           x, w_inT, b_in, wT1, xlr1, N);
    }
    // ---- fused layer 1 (gather + online softmax + bias + elu) -> bf16 ----
    hipLaunchKernelGGL(gatv2_l1_fused_kernel, dim3((N + 3) / 4), blk, 0, stream,
                       xlr1, row, src_sorted, att1, b1, out1, N);
    // ---- layer 2 transform: combined MFMA GEMM -> xlr2 [N][256] ----
    {
        dim3 grid(2 * HID / 128, nRowBlk);
        hipLaunchKernelGGL((mfma_gemm_kernel<0, __hip_bfloat16>), grid, blk, 0, stream,
                           out1, wT2, (const float*)nullptr, xlr2, N, HC1, 2 * HID);
    }
    // ---- fused layer 2 + classifier + log_softmax -> d_out ----
    hipLaunchKernelGGL(gatv2_l2_final_kernel, dim3((N + 3) / 4), blk, 0, stream,
                       xlr2, row, src_sorted, att2, b2, w_out, b_out, out, N);
}